// Round 3
// baseline (47.304 us; speedup 1.0000x reference)
//
#include <hip/hip_runtime.h>

// out[b,u] = sum_d x[b,d] * emb[idx[b],d,u]    B=256, D=1024, U=1024, C=64, fp32
//
// Grid: (64 classes) x (8 u-tiles of 128). Block: 512 threads = 8 waves,
// 2 blocks/CU (LDS 50 KB, __launch_bounds__(512,4) -> VGPR<=128) so one
// block's prologue/epilogue overlaps the other's HBM streaming.
//   - block scans content_idx, builds its class's example list (skip if empty)
//   - wave w owns d-range [w*128, w*128+128); each lane owns 2 consecutive u (float2)
//   - MC=12 examples per pass (single pass for essentially all classes)
//   - x rows staged in LDS, broadcast-read as float4 per 4-d group
//   - epilogue: ALL 12 accumulators staged into the dead xs region at once
//     (12 x 512 float2 = 48 KB), ONE barrier, 12 parallel 64-lane reductions

#define B_N 256
#define D_N 1024
#define U_N 1024
#define C_N 64
#define MC  12
#define NW  8
#define TPB 512
#define UT  128   // u per block

__device__ __forceinline__ void fma2(float2& a, const float2& e, float s) {
    a.x = fmaf(e.x, s, a.x);
    a.y = fmaf(e.y, s, a.y);
}

__global__ __launch_bounds__(TPB, 4) void content_gather_gemv(
    const int* __restrict__ idx,
    const float* __restrict__ x,
    const float* __restrict__ emb,
    float* __restrict__ out)
{
    __shared__ __align__(16) float smem[MC * D_N]; // 48 KB: xs in d-loop, red in epilogue
    __shared__ int bs[B_N];
    __shared__ int cnt;

    const int c    = blockIdx.x;     // class
    const int ut   = blockIdx.y;     // u-tile (128 u)
    const int tid  = threadIdx.x;    // 0..511
    const int wave = tid >> 6;       // 0..7 -> d-slice of 128
    const int lane = tid & 63;       // -> 2 u's

    if (tid == 0) cnt = 0;
    __syncthreads();
    if (tid < B_N && idx[tid] == c) {
        bs[atomicAdd(&cnt, 1)] = tid;   // order irrelevant: per-b results independent
    }
    __syncthreads();
    const int M = cnt;
    if (M == 0) return;

    const int u0 = ut * UT + lane * 2;
    const int d0 = wave * (D_N / NW);           // 128 d per wave
    const float* ebase = emb + ((size_t)c * D_N + d0) * U_N + u0;

    for (int base = 0; base < M; base += MC) {
        const int mc = min(MC, M - base);

        // ---- stage x rows into LDS (zero-pad unused slots) ----
        #pragma unroll
        for (int j = 0; j < MC; ++j) {
            float2 v = make_float2(0.f, 0.f);
            if (j < mc) v = *(const float2*)(x + (size_t)bs[base + j] * D_N + tid * 2);
            *(float2*)&smem[j * D_N + tid * 2] = v;
        }
        __syncthreads();

        float2 acc[MC];
        #pragma unroll
        for (int j = 0; j < MC; ++j) acc[j] = make_float2(0.f, 0.f);

        const bool m4 = (mc > 4);   // block-uniform
        const bool m8 = (mc > 8);

        // ---- main loop: 128 d per wave, 4 rows per iteration (32 iters) ----
        const float* ep = ebase;
        for (int dg = 0; dg < (D_N / NW) / 4; ++dg) {
            float2 e0 = *(const float2*)(ep);
            float2 e1 = *(const float2*)(ep + U_N);
            float2 e2 = *(const float2*)(ep + 2 * U_N);
            float2 e3 = *(const float2*)(ep + 3 * U_N);
            ep += 4 * U_N;
            const int dx = d0 + dg * 4;

            #pragma unroll
            for (int j = 0; j < 4; ++j) {
                float4 xv = *(const float4*)&smem[j * D_N + dx];  // broadcast
                fma2(acc[j], e0, xv.x); fma2(acc[j], e1, xv.y);
                fma2(acc[j], e2, xv.z); fma2(acc[j], e3, xv.w);
            }
            if (m4) {
                #pragma unroll
                for (int j = 4; j < 8; ++j) {
                    float4 xv = *(const float4*)&smem[j * D_N + dx];
                    fma2(acc[j], e0, xv.x); fma2(acc[j], e1, xv.y);
                    fma2(acc[j], e2, xv.z); fma2(acc[j], e3, xv.w);
                }
            }
            if (m8) {
                #pragma unroll
                for (int j = 8; j < MC; ++j) {
                    float4 xv = *(const float4*)&smem[j * D_N + dx];
                    fma2(acc[j], e0, xv.x); fma2(acc[j], e1, xv.y);
                    fma2(acc[j], e2, xv.z); fma2(acc[j], e3, xv.w);
                }
            }
        }

        __syncthreads();   // xs dead; reuse smem as reduction buffer

        // ---- single-barrier epilogue ----
        float2* red = (float2*)smem;            // [MC][512] float2 = 48 KB
        #pragma unroll
        for (int j = 0; j < MC; ++j) {
            if (j < mc) red[j * TPB + tid] = acc[j];   // j static: acc in regs
        }
        __syncthreads();

        // waves 0..7 reduce j=wave; waves 0..3 also j=wave+8
        #pragma unroll
        for (int rep = 0; rep < 2; ++rep) {
            const int j = wave + rep * NW;
            if (j < mc && (rep == 0 || wave < 4)) {
                float2 s = red[j * TPB + lane];
                #pragma unroll
                for (int w = 1; w < NW; ++w) {
                    float2 a = red[j * TPB + w * 64 + lane];
                    s.x += a.x; s.y += a.y;
                }
                *(float2*)(out + (size_t)bs[base + j] * U_N + ut * UT + lane * 2) = s;
            }
        }
        __syncthreads();   // protect xs restage if another chunk follows
    }
}

extern "C" void kernel_launch(void* const* d_in, const int* in_sizes, int n_in,
                              void* d_out, int out_size, void* d_ws, size_t ws_size,
                              hipStream_t stream) {
    const int*   idx = (const int*)d_in[0];
    const float* x   = (const float*)d_in[1];
    const float* emb = (const float*)d_in[2];
    float*       out = (float*)d_out;

    dim3 grid(C_N, U_N / UT);   // 64 x 8 = 512 blocks, 2 per CU
    dim3 block(TPB);
    content_gather_gemv<<<grid, block, 0, stream>>>(idx, x, emb, out);
}